// Round 6
// baseline (1469.001 us; speedup 1.0000x reference)
//
#include <hip/hip_runtime.h>
#include <hip/hip_bf16.h>
#include <stdint.h>

#define BATCH 64
#define SEQ   2048
#define HID   1024
#define EDIM  2048   // 2*HID

#define BM 128        // rows per block
#define BN 128        // cols per block (8 n-slices)
#define BK 32
#define KSTEPS (EDIM / BK)   // 64
#define BS (BATCH * SEQ)

typedef __bf16 bf16x8 __attribute__((ext_vector_type(8)));
typedef float  f32x16 __attribute__((ext_vector_type(16)));
typedef float  f32x4v __attribute__((ext_vector_type(4)));

__device__ __forceinline__ unsigned short f2bf(float x) {
    __hip_bfloat16 h = __float2bfloat16(x);
    return __builtin_bit_cast(unsigned short, h);
}

__device__ __forceinline__ uint4 pack8(f32x4v f0, f32x4v f1) {
    uint4 r;
    r.x = (unsigned)f2bf(f0.x) | ((unsigned)f2bf(f0.y) << 16);
    r.y = (unsigned)f2bf(f0.z) | ((unsigned)f2bf(f0.w) << 16);
    r.z = (unsigned)f2bf(f1.x) | ((unsigned)f2bf(f1.y) << 16);
    r.w = (unsigned)f2bf(f1.z) | ((unsigned)f2bf(f1.w) << 16);
    return r;
}

__device__ __forceinline__ void gload16(const void* g, void* l) {
    __builtin_amdgcn_global_load_lds(
        (const __attribute__((address_space(1))) void*)g,
        (__attribute__((address_space(3))) void*)l, 16, 0, 0);
}

// A-tile byte address: row-major 64B rows, XOR swizzle -> low-conflict b128 reads
__device__ __forceinline__ int a_addr(int row, int g) {
    return ((row << 6) + (g << 4)) ^ ((row & 7) << 4);
}

// ---------------- prep: W_h (EDIM x HID fp32) -> Wt bf16, layout:
// element (h,e) at Wt[(e>>3)*8192 + (h>>7)*1024 + (h&127)*8 + (e&7)]
// => per (k-step granule, 128-col n-slice): 1024 contiguous shorts (2KB)
__global__ void wh_transpose_kernel(const float* __restrict__ Wh,
                                    unsigned short* __restrict__ Wt) {
    __shared__ float tile[32][33];
    int bx = blockIdx.x & 63;    // e-tile
    int by = blockIdx.x >> 6;    // h-tile
    int e0 = bx * 32, h0 = by * 32;
    int tx = threadIdx.x & 31, ty = threadIdx.x >> 5;   // 32 x 8
    #pragma unroll
    for (int i = 0; i < 4; ++i)
        tile[ty + 8 * i][tx] = Wh[(size_t)(e0 + ty + 8 * i) * HID + h0 + tx];
    __syncthreads();
    if (ty < 4) {
        uint4 wv;
        unsigned short* ws = (unsigned short*)&wv;
        #pragma unroll
        for (int j = 0; j < 8; ++j) ws[j] = f2bf(tile[ty * 8 + j][tx]);
        int h = h0 + tx;
        *(uint4*)&Wt[(size_t)((e0 >> 3) + ty) * 8192 + (h >> 7) * 1024 + (h & 127) * 8] = wv;
    }
}

// ---------------- prep: dec_proj = decoder_hidden @ W_d  (fp32, (B,HID))
__global__ void dec_proj_kernel(const float* __restrict__ dec,
                                const float* __restrict__ Wd,
                                float* __restrict__ dp) {
    int gid = blockIdx.x * 256 + threadIdx.x;
    int b = gid >> 10, h = gid & 1023;
    const float* dr = dec + b * HID;
    float acc = 0.f;
    #pragma unroll 4
    for (int k = 0; k < HID; ++k) acc = fmaf(dr[k], Wd[(size_t)k * HID + h], acc);
    dp[gid] = acc;
}

#define MFMA32(a, bfv, c) __builtin_amdgcn_mfma_f32_32x32x16_bf16(a, bfv, c, 0, 0, 0)

// ---------------- main fused scores kernel: 128x128 tile, 4 waves, 33.5KB LDS,
// 4 blocks/CU (m114 wave-level overlap). ns = bid&7 -> one B-slice per XCD.
__global__ __launch_bounds__(256, 4) void scores_kernel(
    const float* __restrict__ enc, const float* __restrict__ cov,
    const unsigned short* __restrict__ Wt, const float* __restrict__ dp,
    const float* __restrict__ Wc, const float* __restrict__ vv,
    float* __restrict__ spart_out)
{
    __shared__ unsigned short Bl[2][4096];   // [buf][g*1024 + n*8], 8KB/buf
    __shared__ char Al[2][8192];             // [buf][swizzled 128x64B]
    __shared__ float cov_s[BM];
    __shared__ float sred[BM][2];

    const int tid  = threadIdx.x;
    const int lane = tid & 63;
    const int w    = tid >> 6;       // 0..3
    const int wr   = w >> 1;         // 0..1 : 64-row half
    const int wc   = w & 1;          // 0..1 : 64-col half
    const int l31  = lane & 31;
    const int hi   = lane >> 5;

    const int bid    = blockIdx.x;
    const int ns     = bid & 7;              // n-slice (XCD-pinned)
    const int mindex = bid >> 3;             // 0..1023
    const int b      = mindex >> 4;
    const int s0     = (mindex & 15) * BM;

    const float* Abase = enc + (size_t)(b * SEQ + s0) * EDIM;
    const int arow = tid >> 1;               // 0..127
    const int agb  = (tid & 1) * 2;          // granule base 0 or 2

    // B source: wave w stages granule w of each k-step; 2x 16B per lane
    const unsigned short* Bw = Wt + (size_t)w * 8192 + ns * 1024 + (size_t)lane * 8;

    f32x16 acc[2][2];
    #pragma unroll
    for (int mi = 0; mi < 2; ++mi)
        #pragma unroll
        for (int nj = 0; nj < 2; ++nj)
            #pragma unroll
            for (int r = 0; r < 16; ++r) acc[mi][nj][r] = 0.f;

    if (tid < BM) cov_s[tid] = cov[b * SEQ + s0 + tid];

    // prologue: stage k-step 0 into buffer 0
    {
        gload16(Bw,       &Bl[0][w * 1024 + lane * 8]);
        gload16(Bw + 512, &Bl[0][w * 1024 + 512 + lane * 8]);
        #pragma unroll
        for (int j = 0; j < 2; ++j) {
            const int g = agb + j;
            const float* ap = Abase + (size_t)arow * EDIM + g * 8;
            f32x4v f0 = *(const f32x4v*)ap;
            f32x4v f1 = *(const f32x4v*)(ap + 4);
            *(uint4*)&Al[0][a_addr(arow, g)] = pack8(f0, f1);
        }
    }
    __syncthreads();

    for (int kk = 0; kk < KSTEPS; ++kk) {
        const int cur = kk & 1, nxt = cur ^ 1;
        f32x4v a00, a01, a10, a11;

        if (kk + 1 < KSTEPS) {
            // issue next B tile (global_load_lds) and next A reg loads early
            const unsigned short* bs = Bw + (size_t)(kk + 1) * 32768;
            gload16(bs,       &Bl[nxt][w * 1024 + lane * 8]);
            gload16(bs + 512, &Bl[nxt][w * 1024 + 512 + lane * 8]);
            const float* ap = Abase + (size_t)arow * EDIM + (kk + 1) * BK + agb * 8;
            a00 = *(const f32x4v*)ap;       a01 = *(const f32x4v*)(ap + 4);
            a10 = *(const f32x4v*)(ap + 8); a11 = *(const f32x4v*)(ap + 12);
        }

        #pragma unroll
        for (int ks = 0; ks < 2; ++ks) {
            const int g = 2 * ks + hi;
            bf16x8 afr[2], bfr[2];
            #pragma unroll
            for (int mi = 0; mi < 2; ++mi)
                afr[mi] = *(const bf16x8*)(&Al[cur][a_addr(wr * 64 + mi * 32 + l31, g)]);
            #pragma unroll
            for (int nj = 0; nj < 2; ++nj)
                bfr[nj] = *(const bf16x8*)(&Bl[cur][g * 1024 + (wc * 64 + nj * 32 + l31) * 8]);
            #pragma unroll
            for (int mi = 0; mi < 2; ++mi)
                #pragma unroll
                for (int nj = 0; nj < 2; ++nj)
                    acc[mi][nj] = MFMA32(afr[mi], bfr[nj], acc[mi][nj]);
        }

        if (kk + 1 < KSTEPS) {
            *(uint4*)&Al[nxt][a_addr(arow, agb)]     = pack8(a00, a01);
            *(uint4*)&Al[nxt][a_addr(arow, agb + 1)] = pack8(a10, a11);
        }
        __syncthreads();
    }

    // epilogue: + dec_proj + cov*W_c -> tanh -> * v, partial-reduce this slice
    float dv[2], wcv[2], vvv[2];
    #pragma unroll
    for (int nj = 0; nj < 2; ++nj) {
        const int h = ns * BN + wc * 64 + nj * 32 + l31;
        dv[nj]  = dp[b * HID + h];
        wcv[nj] = Wc[h];
        vvv[nj] = vv[h];
    }
    #pragma unroll
    for (int mi = 0; mi < 2; ++mi) {
        #pragma unroll
        for (int r = 0; r < 16; ++r) {
            const int row = wr * 64 + mi * 32 + (r & 3) + 8 * (r >> 2) + 4 * hi;
            const float cv = cov_s[row];
            float x = 0.f;
            #pragma unroll
            for (int nj = 0; nj < 2; ++nj) {
                float pre = acc[mi][nj][r] + dv[nj] + cv * wcv[nj];
                float pc = fminf(pre, 20.0f);       // tanh(20)==1 in fp32
                float e2 = __expf(2.0f * pc);
                x = fmaf((e2 - 1.0f) / (e2 + 1.0f), vvv[nj], x);
            }
            x += __shfl_xor(x, 1);
            x += __shfl_xor(x, 2);
            x += __shfl_xor(x, 4);
            x += __shfl_xor(x, 8);
            x += __shfl_xor(x, 16);
            if (l31 == 0) sred[row][wc] = x;
        }
    }
    __syncthreads();
    if (tid < BM)
        spart_out[(size_t)ns * BS + b * SEQ + s0 + tid] = sred[tid][0] + sred[tid][1];
}

// ---------------- softmax + coverage_new (sums the 8 n-slice partial scores)
__global__ void softmax_kernel(const float* __restrict__ spart,
                               const int* __restrict__ mask,
                               const float* __restrict__ cov,
                               float* __restrict__ out)
{
    __shared__ float red[8];
    int b = blockIdx.x, tid = threadIdx.x;   // 256 threads
    float vals[8];
    float mx = -1e30f;
    #pragma unroll
    for (int i = 0; i < 8; ++i) {
        int s = tid + i * 256;
        float sc = 0.f;
        #pragma unroll
        for (int k = 0; k < 8; ++k) sc += spart[(size_t)k * BS + b * SEQ + s];
        sc = (mask[b * SEQ + s] == 0) ? -10000.0f : sc;
        vals[i] = sc;
        mx = fmaxf(mx, sc);
    }
    for (int m = 1; m < 64; m <<= 1) mx = fmaxf(mx, __shfl_xor(mx, m));
    if ((tid & 63) == 0) red[tid >> 6] = mx;
    __syncthreads();
    mx = fmaxf(fmaxf(red[0], red[1]), fmaxf(red[2], red[3]));
    float sum = 0.f;
    #pragma unroll
    for (int i = 0; i < 8; ++i) { vals[i] = __expf(vals[i] - mx); sum += vals[i]; }
    for (int m = 1; m < 64; m <<= 1) sum += __shfl_xor(sum, m);
    if ((tid & 63) == 0) red[4 + (tid >> 6)] = sum;
    __syncthreads();
    sum = red[4] + red[5] + red[6] + red[7];
    float inv = 1.0f / sum;
    float* attn = out + BATCH * EDIM;
    float* covn = attn + BATCH * SEQ;
    #pragma unroll
    for (int i = 0; i < 8; ++i) {
        int s = tid + i * 256;
        float w = vals[i] * inv;
        attn[b * SEQ + s] = w;
        covn[b * SEQ + s] = cov[b * SEQ + s] + w;
    }
}

// ---------------- context = attn @ encoder_outputs  (streaming, 1 GiB read)
__global__ void context_kernel(const float* __restrict__ enc,
                               const float* __restrict__ attn,
                               float* __restrict__ ctx)
{
    __shared__ float w_s[SEQ];
    int b  = blockIdx.x >> 3;
    int e0 = (blockIdx.x & 7) * 256;
    int tid = threadIdx.x;
    for (int i = tid; i < SEQ; i += 256) w_s[i] = attn[b * SEQ + i];
    __syncthreads();
    const float* ep = enc + (size_t)b * SEQ * EDIM + e0 + tid;
    float acc = 0.f;
    #pragma unroll 8
    for (int s = 0; s < SEQ; ++s)
        acc = fmaf(w_s[s], __builtin_nontemporal_load(ep + (size_t)s * EDIM), acc);
    ctx[b * EDIM + e0 + tid] = acc;
}

extern "C" void kernel_launch(void* const* d_in, const int* in_sizes, int n_in,
                              void* d_out, int out_size, void* d_ws, size_t ws_size,
                              hipStream_t stream) {
    const float* dec  = (const float*)d_in[0];
    const float* enc  = (const float*)d_in[1];
    const float* cov  = (const float*)d_in[2];
    const int*   mask = (const int*)d_in[3];
    const float* Wh   = (const float*)d_in[4];
    const float* Wd   = (const float*)d_in[5];
    const float* Wc   = (const float*)d_in[6];
    const float* v    = (const float*)d_in[7];
    float* out = (float*)d_out;

    unsigned short* Wt = (unsigned short*)d_ws;                        // 4 MiB bf16
    float* dp    = (float*)((char*)d_ws + (size_t)HID * EDIM * 2);     // 256 KiB
    float* spart = dp + BATCH * HID;                                   // 8 x 512 KiB

    wh_transpose_kernel<<<dim3(64 * 32), dim3(256), 0, stream>>>(Wh, Wt);
    dec_proj_kernel<<<dim3(BATCH * HID / 256), dim3(256), 0, stream>>>(dec, Wd, dp);
    scores_kernel<<<dim3((SEQ * BATCH / BM) * 8), dim3(256), 0, stream>>>(
        enc, cov, Wt, dp, Wc, v, spart);
    softmax_kernel<<<dim3(BATCH), dim3(256), 0, stream>>>(spart, mask, cov, out);
    context_kernel<<<dim3(BATCH * (EDIM / 256)), dim3(256), 0, stream>>>(enc, out + BATCH * EDIM, out);
}